// Round 1
// 1659.897 us; speedup vs baseline: 1.0480x; 1.0480x over previous
//
#include <hip/hip_runtime.h>
#include <hip/hip_bf16.h>

using bf16 = __hip_bfloat16;
typedef short s16x8 __attribute__((ext_vector_type(8)));
typedef float f32x4 __attribute__((ext_vector_type(4)));

static constexpr int D  = 2048;
static constexpr int H  = 16;
static constexpr int FF = 8192;
static constexpr int S  = 1024;
static constexpr int NB = 2;        // batch
static constexpr int DH = 128;
static constexpr int L  = 2;
static constexpr int BS = NB * S;   // 2048 tokens
static constexpr int BH = NB * H;   // 32
static constexpr int D3 = 3 * D;    // 6144

// ---------------------------------------------------------------- utilities
__device__ __forceinline__ float wave_sum(float v) {
#pragma unroll
  for (int o = 32; o > 0; o >>= 1) v += __shfl_down(v, o, 64);
  return v;
}
__device__ __forceinline__ float wave_max(float v) {
#pragma unroll
  for (int o = 32; o > 0; o >>= 1) v = fmaxf(v, __shfl_down(v, o, 64));
  return v;
}

__device__ __forceinline__ void gll16(const void* g, void* l) {
  __builtin_amdgcn_global_load_lds(
      (const __attribute__((address_space(1))) unsigned int*)g,
      (__attribute__((address_space(3))) unsigned int*)l, 16, 0, 0);
}

__device__ __forceinline__ float gelu_tanh(float x) {
  return 0.5f * x * (1.0f + tanhf(0.7978845608028654f * (x + 0.044715f * x * x * x)));
}

__device__ __forceinline__ void stv(float* p, long i, float v) { p[i] = v; }
__device__ __forceinline__ void stv(bf16* p, long i, float v)  { p[i] = __float2bfloat16(v); }

// ---------------------------------------------------------------- GEMM 128² (kept for QK / PV / Wo)
// C[M,N] = A[M,K] (bf16 row-major, lda) x B'[N,K] (bf16 row-major, ldb)
// EPI: 0 = f32 store, 1 = bf16 store, 2 = f32 residual add, 3 = bf16 gelu store
template <int EPI>
__launch_bounds__(256)
__global__ void gemm_k(const bf16* __restrict__ A, int lda, long sAb, long sAh,
                       const bf16* __restrict__ Bt, int ldb, long sBb, long sBh,
                       void* __restrict__ Cp, int ldc, long sCb, long sCh,
                       const float* __restrict__ resid, int K, int nH) {
  __shared__ __align__(16) bf16 lsA[2][128 * 32];
  __shared__ __align__(16) bf16 lsB[2][128 * 32];
  const int tid = threadIdx.x;
  const int zb = blockIdx.z / nH, zh = blockIdx.z % nH;
  const int m0 = blockIdx.y * 128, n0 = blockIdx.x * 128;
  const int sr = tid >> 2, sc = (tid & 3) * 8;
  const bf16* Ag = A + zb * sAb + zh * sAh + (long)(m0 + sr) * lda + sc;
  const bf16* Bg = Bt + zb * sBb + zh * sBh + (long)(n0 + sr) * ldb + sc;
  const long a64 = 64L * lda, b64 = 64L * ldb;

  const int lane = tid & 63, wv = tid >> 6;
  const int wm = (wv >> 1) * 64, wn = (wv & 1) * 64;
  const int fl = lane & 15, fg = lane >> 4;

  f32x4 acc[4][4];
#pragma unroll
  for (int i = 0; i < 4; i++)
#pragma unroll
    for (int j = 0; j < 4; j++) acc[i][j] = (f32x4){0.f, 0.f, 0.f, 0.f};

  gll16(Ag, lsA[0] + tid * 8);
  gll16(Ag + a64, lsA[0] + 2048 + tid * 8);
  gll16(Bg, lsB[0] + tid * 8);
  gll16(Bg + b64, lsB[0] + 2048 + tid * 8);
  __syncthreads();

  int it = 0;
  for (int k0 = 0; k0 < K; k0 += 32, it ^= 1) {
    const int nxt = it ^ 1;
    if (k0 + 32 < K) {
      gll16(Ag + k0 + 32, lsA[nxt] + tid * 8);
      gll16(Ag + a64 + k0 + 32, lsA[nxt] + 2048 + tid * 8);
      gll16(Bg + k0 + 32, lsB[nxt] + tid * 8);
      gll16(Bg + b64 + k0 + 32, lsB[nxt] + 2048 + tid * 8);
    }
    s16x8 af[4], bq[4];
#pragma unroll
    for (int i = 0; i < 4; i++) {
      af[i] = *(const s16x8*)(lsA[it] + (wm + i * 16 + fl) * 32 + fg * 8);
      bq[i] = *(const s16x8*)(lsB[it] + (wn + i * 16 + fl) * 32 + fg * 8);
    }
#pragma unroll
    for (int i = 0; i < 4; i++)
#pragma unroll
      for (int j = 0; j < 4; j++)
        acc[i][j] = __builtin_amdgcn_mfma_f32_16x16x32_bf16(af[i], bq[j], acc[i][j], 0, 0, 0);
    __syncthreads();
  }

  const long offC = zb * sCb + zh * sCh;
#pragma unroll
  for (int i = 0; i < 4; i++) {
#pragma unroll
    for (int j = 0; j < 4; j++) {
      const int row = m0 + wm + i * 16 + fg * 4;
      const int col = n0 + wn + j * 16 + fl;
#pragma unroll
      for (int r = 0; r < 4; r++) {
        const long ci = offC + (long)(row + r) * ldc + col;
        float v = acc[i][j][r];
        if (EPI == 0) {
          ((float*)Cp)[ci] = v;
        } else if (EPI == 1) {
          ((bf16*)Cp)[ci] = __float2bfloat16(v);
        } else if (EPI == 2) {
          ((float*)Cp)[ci] = v + resid[ci];
        } else {
          ((bf16*)Cp)[ci] = __float2bfloat16(gelu_tanh(v));
        }
      }
    }
  }
}

// ---------------------------------------------------------------- GEMM 256² 8-phase
// 256x256 tile, BK=64, 512 threads = 8 waves (2M x 4N), wave tile 128x64.
// LDS 128 KiB double-buffered. st-swizzle: 16B slot ^= (row&7), applied by
// inverse-swizzling the GLOBAL source (global_load_lds dest must be linear)
// and swizzling the ds_read address. Counted vmcnt(6) at phases 4/8 only.
// Region-death schedule (per buffer: A0/A1 = qm halves, B0/B1 = qn halves):
//   ph1 reads A0,B0 (12 ds) | ph2 reads B1 (4) | ph3 reads A1 (8) | ph4 none
// so staging (1 half per phase, 2 gll each):
//   ph1:A1(t+1)  ph2:A0(t+2) ph3:B0(t+2) ph4:B1(t+2) ph5:A1(t+2)
//   ph6:A0(t+3)  ph7:B0(t+3) ph8:B1(t+3)   -- each target region is dead.
template <int EPI>
__launch_bounds__(512, 2)
__global__ void gemm256_k(const bf16* __restrict__ A, int lda, long sAb, long sAh,
                          const bf16* __restrict__ Bt, int ldb, long sBb, long sBh,
                          void* __restrict__ Cp, int ldc, long sCb, long sCh,
                          int K, int nH) {
  __shared__ __align__(16) bf16 lsA[2][256 * 64];   // 64 KB
  __shared__ __align__(16) bf16 lsB[2][256 * 64];   // 64 KB
  const int tid = threadIdx.x;
  const int zb = blockIdx.z / nH, zh = blockIdx.z % nH;
  const int m0 = blockIdx.y * 256, n0 = blockIdx.x * 256;

  // staging: thread t covers row (t>>3) of a 64-row gll chunk, 16B col chunk
  // (t&7), source col chunk inverse-swizzled by row&7.
  const int sr = tid >> 3;
  const int sc = (tid & 7) ^ (sr & 7);
  const bf16* Ag = A + zb * sAb + zh * sAh + (long)(m0 + sr) * lda + sc * 8;
  const bf16* Bg = Bt + zb * sBb + zh * sBh +
                   (long)(n0 + (tid >> 8) * 64 + (sr & 31)) * ldb + sc * 8;

  const int lane = tid & 63, wv = tid >> 6;
  const int wm = wv >> 2;          // 0..1  (M group: rows wm*128..+128)
  const int wn = wv & 3;           // 0..3  (N group: cols wn*64..+64)
  const int fl = lane & 15, fg = lane >> 4;

  // ds_read addressing (elements): row lr -> lr*64 + swizzled 8-elem slot
  const int aob = (wm * 64 + fl) * 64;
  const int bob = (wn * 32 + fl) * 64;
  const int s0 = ((fg) ^ (fl & 7)) * 8;        // kk=0
  const int s1 = ((4 + fg) ^ (fl & 7)) * 8;    // kk=1

  s16x8 a[4][2];        // A frags of current qm half: [mf][kk]
  s16x8 bq[2][2][2];    // B frags, both qn halves live: [qn][nf][kk]
  f32x4 acc[2][4][2][2];
#pragma unroll
  for (int qm = 0; qm < 2; qm++)
#pragma unroll
    for (int mf = 0; mf < 4; mf++)
#pragma unroll
      for (int qn = 0; qn < 2; qn++)
#pragma unroll
        for (int nf = 0; nf < 2; nf++) acc[qm][mf][qn][nf] = (f32x4){0.f, 0.f, 0.f, 0.f};

#define STAGE_A(buf, qm, kt)                                                  \
  do {                                                                        \
    const bf16* _s = Ag + (long)((qm) * 64) * lda + (kt) * 64;                \
    gll16(_s, lsA[buf] + (qm) * 8192 + tid * 8);                              \
    gll16(_s + 128L * lda, lsA[buf] + (qm) * 8192 + 4096 + tid * 8);          \
  } while (0)
#define STAGE_B(buf, qn, kt)                                                  \
  do {                                                                        \
    const bf16* _s = Bg + (long)((qn) * 32) * ldb + (kt) * 64;                \
    gll16(_s, lsB[buf] + (qn) * 8192 + tid * 8);                              \
    gll16(_s + 128L * ldb, lsB[buf] + (qn) * 8192 + 4096 + tid * 8);          \
  } while (0)
#define LDA8(buf, qm)                                                         \
  do {                                                                        \
    const bf16* _p = lsA[buf] + (qm) * 8192 + aob;                            \
    a[0][0] = *(const s16x8*)(_p + s0);        a[0][1] = *(const s16x8*)(_p + s1);        \
    a[1][0] = *(const s16x8*)(_p + 1024 + s0); a[1][1] = *(const s16x8*)(_p + 1024 + s1); \
    a[2][0] = *(const s16x8*)(_p + 2048 + s0); a[2][1] = *(const s16x8*)(_p + 2048 + s1); \
    a[3][0] = *(const s16x8*)(_p + 3072 + s0); a[3][1] = *(const s16x8*)(_p + 3072 + s1); \
  } while (0)
#define LDB4(buf, qn)                                                         \
  do {                                                                        \
    const bf16* _p = lsB[buf] + (qn) * 8192 + bob;                            \
    bq[qn][0][0] = *(const s16x8*)(_p + s0);        bq[qn][0][1] = *(const s16x8*)(_p + s1);        \
    bq[qn][1][0] = *(const s16x8*)(_p + 1024 + s0); bq[qn][1][1] = *(const s16x8*)(_p + 1024 + s1); \
  } while (0)
#define MM16(qm, qn)                                                          \
  do {                                                                        \
    _Pragma("unroll") for (int mf = 0; mf < 4; ++mf) {                        \
      acc[qm][mf][qn][0] = __builtin_amdgcn_mfma_f32_16x16x32_bf16(           \
          a[mf][0], bq[qn][0][0], acc[qm][mf][qn][0], 0, 0, 0);               \
      acc[qm][mf][qn][1] = __builtin_amdgcn_mfma_f32_16x16x32_bf16(           \
          a[mf][0], bq[qn][1][0], acc[qm][mf][qn][1], 0, 0, 0);               \
      acc[qm][mf][qn][0] = __builtin_amdgcn_mfma_f32_16x16x32_bf16(           \
          a[mf][1], bq[qn][0][1], acc[qm][mf][qn][0], 0, 0, 0);               \
      acc[qm][mf][qn][1] = __builtin_amdgcn_mfma_f32_16x16x32_bf16(           \
          a[mf][1], bq[qn][1][1], acc[qm][mf][qn][1], 0, 0, 0);               \
    }                                                                         \
  } while (0)
#define PHASE_TAIL(qm, qn)                                                    \
  __builtin_amdgcn_s_barrier();                                               \
  asm volatile("s_waitcnt lgkmcnt(0)" ::: "memory");                          \
  __builtin_amdgcn_sched_barrier(0);                                          \
  __builtin_amdgcn_s_setprio(1);                                              \
  MM16(qm, qn);                                                               \
  __builtin_amdgcn_s_setprio(0);

  const int NT = K >> 6;  // K-tiles of 64; NT even, >= 2

  // prologue: tile0 fully (first 4 halves issued), tile1's A0/B0/B1.
  STAGE_A(0, 0, 0); STAGE_B(0, 0, 0); STAGE_B(0, 1, 0); STAGE_A(0, 1, 0);
  STAGE_A(1, 0, 1); STAGE_B(1, 0, 1); STAGE_B(1, 1, 1);
  asm volatile("s_waitcnt vmcnt(6)" ::: "memory");  // tile0 complete
  __builtin_amdgcn_s_barrier();

  for (int t = 0; t < NT; t += 2) {
    const bool nl = (t + 2 < NT);
    // ---- ph1: (t, qm0, qn0)
    LDA8(0, 0);
    LDB4(0, 0);
    STAGE_A(1, 1, t + 1);
    PHASE_TAIL(0, 0);
    __builtin_amdgcn_s_barrier();
    // ---- ph2: (t, qm0, qn1)
    LDB4(0, 1);
    if (nl) STAGE_A(0, 0, t + 2);
    PHASE_TAIL(0, 1);
    __builtin_amdgcn_s_barrier();
    // ---- ph3: (t, qm1, qn0)
    LDA8(0, 1);
    if (nl) STAGE_B(0, 0, t + 2);
    PHASE_TAIL(1, 0);
    __builtin_amdgcn_s_barrier();
    // ---- ph4: (t, qm1, qn1)
    if (nl) STAGE_B(0, 1, t + 2);
    PHASE_TAIL(1, 1);
    if (nl) asm volatile("s_waitcnt vmcnt(6)" ::: "memory");
    else    asm volatile("s_waitcnt vmcnt(0)" ::: "memory");
    __builtin_amdgcn_s_barrier();
    // ---- ph5: (t+1, qm0, qn0)
    LDA8(1, 0);
    LDB4(1, 0);
    if (nl) STAGE_A(0, 1, t + 2);
    PHASE_TAIL(0, 0);
    __builtin_amdgcn_s_barrier();
    // ---- ph6: (t+1, qm0, qn1)
    LDB4(1, 1);
    if (nl) STAGE_A(1, 0, t + 3);
    PHASE_TAIL(0, 1);
    __builtin_amdgcn_s_barrier();
    // ---- ph7: (t+1, qm1, qn0)
    LDA8(1, 1);
    if (nl) STAGE_B(1, 0, t + 3);
    PHASE_TAIL(1, 0);
    __builtin_amdgcn_s_barrier();
    // ---- ph8: (t+1, qm1, qn1)
    if (nl) STAGE_B(1, 1, t + 3);
    PHASE_TAIL(1, 1);
    if (nl) asm volatile("s_waitcnt vmcnt(6)" ::: "memory");
    __builtin_amdgcn_s_barrier();
  }

  const long offC = zb * sCb + zh * sCh;
#pragma unroll
  for (int qm = 0; qm < 2; qm++) {
#pragma unroll
    for (int mf = 0; mf < 4; mf++) {
#pragma unroll
      for (int qn = 0; qn < 2; qn++) {
#pragma unroll
        for (int nf = 0; nf < 2; nf++) {
          const int row = m0 + wm * 128 + qm * 64 + mf * 16 + fg * 4;
          const int col = n0 + wn * 64 + qn * 32 + nf * 16 + fl;
#pragma unroll
          for (int r = 0; r < 4; r++) {
            const long ci = offC + (long)(row + r) * ldc + col;
            float v = acc[qm][mf][qn][nf][r];
            if (EPI == 0) {
              ((float*)Cp)[ci] = v;
            } else if (EPI == 1) {
              ((bf16*)Cp)[ci] = __float2bfloat16(v);
            } else {
              ((bf16*)Cp)[ci] = __float2bfloat16(gelu_tanh(v));
            }
          }
        }
      }
    }
  }
#undef STAGE_A
#undef STAGE_B
#undef LDA8
#undef LDB4
#undef MM16
#undef PHASE_TAIL
}

// --------------------------------------------- split-K reduce: x += sum(p[0..3])
__launch_bounds__(256)
__global__ void reduce4_k(const float* __restrict__ p, float* __restrict__ x) {
  const long i = (long)blockIdx.x * 256 + threadIdx.x;  // over BS*D/4 float4s
  const long n = (long)BS * D / 4;
  const float4 a = ((const float4*)p)[i];
  const float4 b = ((const float4*)p)[i + n];
  const float4 c = ((const float4*)p)[i + 2 * n];
  const float4 d2 = ((const float4*)p)[i + 3 * n];
  float4 xv = ((float4*)x)[i];
  xv.x += a.x + b.x + c.x + d2.x;
  xv.y += a.y + b.y + c.y + d2.y;
  xv.z += a.z + b.z + c.z + d2.z;
  xv.w += a.w + b.w + c.w + d2.w;
  ((float4*)x)[i] = xv;
}

// ------------------------------------------------- weight transpose + cast
__launch_bounds__(256)
__global__ void transcast_k(const float* __restrict__ in, bf16* __restrict__ out,
                            int R, int C) {
  __shared__ float tile[32][33];
  const int tx = threadIdx.x, ty = threadIdx.y;
  const int c0 = blockIdx.x * 32, r0 = blockIdx.y * 32;
#pragma unroll
  for (int k = 0; k < 4; k++)
    tile[ty + 8 * k][tx] = in[(long)(r0 + ty + 8 * k) * C + c0 + tx];
  __syncthreads();
#pragma unroll
  for (int k = 0; k < 4; k++)
    out[(long)(c0 + ty + 8 * k) * R + r0 + tx] = __float2bfloat16(tile[tx][ty + 8 * k]);
}

// ------------------------------------------------- V transpose per head
__launch_bounds__(256)
__global__ void vtrans_k(const bf16* __restrict__ qkv, bf16* __restrict__ Vt) {
  __shared__ bf16 tile[32][33];
  const int z = blockIdx.z, b = z / H, h = z % H;
  const int d0 = blockIdx.x * 32, s0 = blockIdx.y * 32;
  const int tx = threadIdx.x, ty = threadIdx.y;
#pragma unroll
  for (int k = 0; k < 4; k++)
    tile[ty + 8 * k][tx] =
        qkv[(long)(b * S + s0 + ty + 8 * k) * D3 + 2 * D + h * DH + d0 + tx];
  __syncthreads();
#pragma unroll
  for (int k = 0; k < 4; k++)
    Vt[((long)z * DH + d0 + ty + 8 * k) * S + s0 + tx] = tile[tx][ty + 8 * k];
}

// ---------------------------------------------------------------- LayerNorm
template <typename OutT>
__launch_bounds__(256)
__global__ void ln_k(const float* __restrict__ x, const float* __restrict__ g,
                     const float* __restrict__ bb, OutT* __restrict__ out) {
  __shared__ float sA[4], sB[4];
  const long row = blockIdx.x;
  const int tid = threadIdx.x;
  const float4* xr = (const float4*)(x + row * D);
  float4 v0 = xr[tid], v1 = xr[tid + 256];
  float s = v0.x + v0.y + v0.z + v0.w + v1.x + v1.y + v1.z + v1.w;
  float ss = v0.x * v0.x + v0.y * v0.y + v0.z * v0.z + v0.w * v0.w +
             v1.x * v1.x + v1.y * v1.y + v1.z * v1.z + v1.w * v1.w;
  s = wave_sum(s);
  ss = wave_sum(ss);
  const int lane = tid & 63, wv = tid >> 6;
  if (lane == 0) { sA[wv] = s; sB[wv] = ss; }
  __syncthreads();
  s = sA[0] + sA[1] + sA[2] + sA[3];
  ss = sB[0] + sB[1] + sB[2] + sB[3];
  const float mean = s * (1.f / D);
  const float var = ss * (1.f / D) - mean * mean;
  const float rstd = rsqrtf(var + 1e-5f);
  const float4* gv = (const float4*)g;
  const float4* bv = (const float4*)bb;
  float4 g0 = gv[tid], g1 = gv[tid + 256], c0 = bv[tid], c1 = bv[tid + 256];
  OutT* orow = out + row * D;
  stv(orow, 4 * tid + 0, (v0.x - mean) * rstd * g0.x + c0.x);
  stv(orow, 4 * tid + 1, (v0.y - mean) * rstd * g0.y + c0.y);
  stv(orow, 4 * tid + 2, (v0.z - mean) * rstd * g0.z + c0.z);
  stv(orow, 4 * tid + 3, (v0.w - mean) * rstd * g0.w + c0.w);
  stv(orow, 1024 + 4 * tid + 0, (v1.x - mean) * rstd * g1.x + c1.x);
  stv(orow, 1024 + 4 * tid + 1, (v1.y - mean) * rstd * g1.y + c1.y);
  stv(orow, 1024 + 4 * tid + 2, (v1.z - mean) * rstd * g1.z + c1.z);
  stv(orow, 1024 + 4 * tid + 3, (v1.w - mean) * rstd * g1.w + c1.w);
}

// ---------------------------------------------------------------- embedding
__launch_bounds__(256)
__global__ void embed_k(const int* __restrict__ ids, const float* __restrict__ emb,
                        float* __restrict__ x) {
  const long gid = (long)blockIdx.x * 256 + threadIdx.x;  // over BS * D/4
  const int tok = (int)(gid >> 9);                        // D/4 = 512
  const int c = (int)(gid & 511);
  const int id = ids[tok];
  ((float4*)x)[gid] = ((const float4*)(emb + (long)id * D))[c];
}

// ------------------------------------------- softmax (in-place fp32 -> bf16)
__launch_bounds__(256)
__global__ void softmax_k(float* __restrict__ scores, const int* __restrict__ amask,
                          float scale) {
  __shared__ float sred[4];
  const int q = blockIdx.x, z = blockIdx.y, b = z / H;
  float* row = scores + ((long)z * S + q) * S;
  const int tid = threadIdx.x;
  const int lane = tid & 63, wv = tid >> 6;
  float v[4];
  float mx = -3.4e38f;
#pragma unroll
  for (int i = 0; i < 4; i++) {
    const int k = tid + i * 256;
    const float s = row[k] * scale;
    const bool ok = (k <= q) && (amask[b * S + k] != 0);
    v[i] = s + (ok ? 0.f : -1e9f);
    mx = fmaxf(mx, v[i]);
  }
  mx = wave_max(mx);
  if (lane == 0) sred[wv] = mx;
  __syncthreads();
  mx = fmaxf(fmaxf(sred[0], sred[1]), fmaxf(sred[2], sred[3]));
  __syncthreads();
  float e[4], sm = 0.f;
#pragma unroll
  for (int i = 0; i < 4; i++) {
    e[i] = __expf(v[i] - mx);
    sm += e[i];
  }
  sm = wave_sum(sm);
  if (lane == 0) sred[wv] = sm;
  __syncthreads();
  sm = sred[0] + sred[1] + sred[2] + sred[3];
  const float inv = 1.f / sm;
  bf16* orow = (bf16*)row;  // in-place: all fp32 reads completed before barrier
#pragma unroll
  for (int i = 0; i < 4; i++) orow[tid + i * 256] = __float2bfloat16(e[i] * inv);
}

// ---------------------------------------------------------------- pooling
__launch_bounds__(256)
__global__ void pool_k(const float* __restrict__ hs, const int* __restrict__ amask,
                       float* __restrict__ pooled) {
  const int d = blockIdx.x * 256 + threadIdx.x;
  const int b = blockIdx.y;
  float s = 0.f, cnt = 0.f;
  for (int i = 0; i < S; i++) {
    const float m = (float)amask[b * S + i];
    s += hs[((long)(b * S + i)) * D + d] * m;
    cnt += m;
  }
  pooled[b * D + d] = s / fmaxf(cnt, 1e-9f);
}

// ---------------------------------------------------------------- head
__launch_bounds__(256)
__global__ void head1_k(const float* __restrict__ pooled, const float* __restrict__ Wc1,
                        const float* __restrict__ bc1, float* __restrict__ t) {
  const int j = blockIdx.x * 256 + threadIdx.x;
  const int b = blockIdx.y;
  float s = bc1[j];
  for (int d = 0; d < D; d++) s += pooled[b * D + d] * Wc1[(long)d * D + j];
  t[b * D + j] = tanhf(s);
}

__launch_bounds__(256)
__global__ void head2_k(const float* __restrict__ t, const float* __restrict__ Wc2,
                        const float* __restrict__ bc2, float* __restrict__ out) {
  __shared__ float red[4][4];
  const int tid = threadIdx.x;
  const int lane = tid & 63, wv = tid >> 6;
  float a[4] = {0.f, 0.f, 0.f, 0.f};  // [b*2+c]
  for (int j = tid; j < D; j += 256) {
    const float w0 = Wc2[j * 2 + 0], w1 = Wc2[j * 2 + 1];
    const float t0 = t[j], t1 = t[D + j];
    a[0] += t0 * w0; a[1] += t0 * w1; a[2] += t1 * w0; a[3] += t1 * w1;
  }
#pragma unroll
  for (int c = 0; c < 4; c++) a[c] = wave_sum(a[c]);
  if (lane == 0) {
#pragma unroll
    for (int c = 0; c < 4; c++) red[wv][c] = a[c];
  }
  __syncthreads();
  if (tid == 0) {
    float tot[4];
#pragma unroll
    for (int c = 0; c < 4; c++) tot[c] = red[0][c] + red[1][c] + red[2][c] + red[3][c];
    const float l00 = tot[0] + bc2[0], l01 = tot[1] + bc2[1];
    const float l10 = tot[2] + bc2[0], l11 = tot[3] + bc2[1];
    out[0] = 1.f / (1.f + __expf(l00 - l01));
    out[1] = 1.f / (1.f + __expf(l10 - l11));
  }
}

// ---------------------------------------------------------------- launcher
extern "C" void kernel_launch(void* const* d_in, const int* in_sizes, int n_in,
                              void* d_out, int out_size, void* d_ws, size_t ws_size,
                              hipStream_t stream) {
  (void)in_sizes; (void)n_in; (void)out_size; (void)ws_size;
  const int*   ids   = (const int*)d_in[0];
  const int*   amask = (const int*)d_in[1];
  const float* emb   = (const float*)d_in[2];
  const float* ln1g  = (const float*)d_in[3];
  const float* ln1b  = (const float*)d_in[4];
  const float* Wqkv  = (const float*)d_in[5];
  const float* Wo    = (const float*)d_in[6];
  const float* ln2g  = (const float*)d_in[7];
  const float* ln2b  = (const float*)d_in[8];
  const float* W1    = (const float*)d_in[9];
  const float* W2    = (const float*)d_in[10];
  const float* lnfg  = (const float*)d_in[11];
  const float* lnfb  = (const float*)d_in[12];
  const float* Wc1   = (const float*)d_in[13];
  const float* bc1   = (const float*)d_in[14];
  const float* Wc2   = (const float*)d_in[15];
  const float* bc2   = (const float*)d_in[16];
  float* out = (float*)d_out;

  char* ws = (char*)d_ws;
  size_t off = 0;
  auto alloc = [&](size_t bytes) {
    size_t r = off;
    off += (bytes + 255) & ~(size_t)255;
    return r;
  };
  bf16* Wqkv_t = (bf16*)(ws + alloc((size_t)D3 * D * 2));
  bf16* Wo_t   = (bf16*)(ws + alloc((size_t)D * D * 2));
  bf16* W1_t   = (bf16*)(ws + alloc((size_t)FF * D * 2));
  bf16* W2_t   = (bf16*)(ws + alloc((size_t)D * FF * 2));
  float* x     = (float*)(ws + alloc((size_t)BS * D * 4));
  bf16* h      = (bf16*)(ws + alloc((size_t)BS * D * 2));
  bf16* qkv    = (bf16*)(ws + alloc((size_t)BS * D3 * 2));
  bf16* Vt     = (bf16*)(ws + alloc((size_t)BH * DH * S * 2));
  bf16* o_buf  = (bf16*)(ws + alloc((size_t)BS * D * 2));
  float* pooled= (float*)(ws + alloc((size_t)NB * D * 4));
  float* tb    = (float*)(ws + alloc((size_t)NB * D * 4));
  char* big    = ws + alloc((size_t)BH * S * S * 4);  // scores / ff+partials / hs union
  float* scores = (float*)big;
  bf16*  ffb    = (bf16*)big;                          // [BS][FF] bf16
  float* hs     = (float*)big;
  float* parts  = (float*)(big + ((size_t)BS * FF * 2 + 255 & ~(size_t)255));

  const float scale = 0.088388347648318447f;  // 1/sqrt(128)
  dim3 blk(256);
  dim3 blk5(512);
  dim3 tblk(32, 8);

  embed_k<<<4096, blk, 0, stream>>>(ids, emb, x);

  for (int l = 0; l < L; l++) {
    transcast_k<<<dim3(D3 / 32, D / 32), tblk, 0, stream>>>(Wqkv + (size_t)l * D * D3, Wqkv_t, D, D3);
    transcast_k<<<dim3(D / 32, D / 32), tblk, 0, stream>>>(Wo + (size_t)l * D * D, Wo_t, D, D);
    transcast_k<<<dim3(FF / 32, D / 32), tblk, 0, stream>>>(W1 + (size_t)l * D * FF, W1_t, D, FF);
    transcast_k<<<dim3(D / 32, FF / 32), tblk, 0, stream>>>(W2 + (size_t)l * FF * D, W2_t, FF, D);

    // h = LN1(x)
    ln_k<bf16><<<BS, blk, 0, stream>>>(x, ln1g + (size_t)l * D, ln1b + (size_t)l * D, h);
    // qkv = h @ Wqkv  (256² 8-phase)
    gemm256_k<1><<<dim3(D3 / 256, BS / 256, 1), blk5, 0, stream>>>(
        h, D, 0, 0, Wqkv_t, D, 0, 0, qkv, D3, 0, 0, D, 1);
    // Vt
    vtrans_k<<<dim3(DH / 32, S / 32, BH), tblk, 0, stream>>>(qkv, Vt);
    // scores = Q @ K^T  (per b,h) — K=128, keep 128² kernel
    gemm_k<0><<<dim3(S / 128, S / 128, BH), blk, 0, stream>>>(
        qkv, D3, (long)S * D3, DH,
        qkv + D, D3, (long)S * D3, DH,
        scores, S, (long)H * S * S, (long)S * S, nullptr, DH, H);
    softmax_k<<<dim3(S, BH), blk, 0, stream>>>(scores, amask, scale);
    // o = attn @ V  (per b,h) — N=128, keep 128² kernel
    gemm_k<1><<<dim3(DH / 128, S / 128, BH), blk, 0, stream>>>(
        (const bf16*)scores, 2 * S, (long)H * 2 * S * S, (long)2 * S * S,
        Vt, S, (long)H * DH * S, (long)DH * S,
        o_buf, D, (long)S * D, DH, nullptr, S, H);
    // x = x + o @ Wo — 64 blocks at 256² would under-occupy, keep 128²
    gemm_k<2><<<dim3(D / 128, BS / 128, 1), blk, 0, stream>>>(
        o_buf, D, 0, 0, Wo_t, D, 0, 0, x, D, 0, 0, x, D, 1);
    // h = LN2(x)
    ln_k<bf16><<<BS, blk, 0, stream>>>(x, ln2g + (size_t)l * D, ln2b + (size_t)l * D, h);
    // ff = gelu(h @ W1)  (256² 8-phase)
    gemm256_k<3><<<dim3(FF / 256, BS / 256, 1), blk5, 0, stream>>>(
        h, D, 0, 0, W1_t, D, 0, 0, ffb, FF, 0, 0, D, 1);
    // x = x + ff @ W2 — split-K=4 (256² 8-phase, 8x8x4 = 256 blocks)
    gemm256_k<0><<<dim3(D / 256, BS / 256, 4), blk5, 0, stream>>>(
        ffb, FF, 0, 2048, W2_t, FF, 0, 2048,
        parts, D, 0, (long)BS * D, 2048, 4);
    reduce4_k<<<dim3(BS * D / 4 / 256), blk, 0, stream>>>(parts, x);
  }

  ln_k<float><<<BS, blk, 0, stream>>>(x, lnfg, lnfb, hs);
  pool_k<<<dim3(D / 256, NB), blk, 0, stream>>>(hs, amask, pooled);
  head1_k<<<dim3(D / 256, NB), blk, 0, stream>>>(pooled, Wc1, bc1, tb);
  head2_k<<<1, blk, 0, stream>>>(tb, Wc2, bc2, out);
}

// Round 3
// 1603.681 us; speedup vs baseline: 1.0848x; 1.0351x over previous
//
#include <hip/hip_runtime.h>
#include <hip/hip_bf16.h>

using bf16 = __hip_bfloat16;
typedef short s16x8 __attribute__((ext_vector_type(8)));
typedef float f32x4 __attribute__((ext_vector_type(4)));

static constexpr int D  = 2048;
static constexpr int H  = 16;
static constexpr int FF = 8192;
static constexpr int S  = 1024;
static constexpr int NB = 2;        // batch
static constexpr int DH = 128;
static constexpr int L  = 2;
static constexpr int BS = NB * S;   // 2048 tokens
static constexpr int BH = NB * H;   // 32
static constexpr int D3 = 3 * D;    // 6144

// ---------------------------------------------------------------- utilities
__device__ __forceinline__ float wave_sum(float v) {
#pragma unroll
  for (int o = 32; o > 0; o >>= 1) v += __shfl_down(v, o, 64);
  return v;
}
__device__ __forceinline__ float grp_max16(float v) {
  v = fmaxf(v, __shfl_xor(v, 1));
  v = fmaxf(v, __shfl_xor(v, 2));
  v = fmaxf(v, __shfl_xor(v, 4));
  v = fmaxf(v, __shfl_xor(v, 8));
  return v;
}
__device__ __forceinline__ float grp_sum16(float v) {
  v += __shfl_xor(v, 1);
  v += __shfl_xor(v, 2);
  v += __shfl_xor(v, 4);
  v += __shfl_xor(v, 8);
  return v;
}

__device__ __forceinline__ void gll16(const void* g, void* l) {
  __builtin_amdgcn_global_load_lds(
      (const __attribute__((address_space(1))) unsigned int*)g,
      (__attribute__((address_space(3))) unsigned int*)l, 16, 0, 0);
}

__device__ __forceinline__ float gelu_tanh(float x) {
  return 0.5f * x * (1.0f + tanhf(0.7978845608028654f * (x + 0.044715f * x * x * x)));
}

__device__ __forceinline__ void stv(float* p, long i, float v) { p[i] = v; }
__device__ __forceinline__ void stv(bf16* p, long i, float v)  { p[i] = __float2bfloat16(v); }

// swizzled LDS fragment read: row-major [128][128] bf16 tile, 16B chunk index
// XOR'd with (row&7); matches staging that inverse-swizzles the global source.
__device__ __forceinline__ s16x8 ldfrag(const bf16* base, int row, int ch) {
  return *(const s16x8*)(base + row * 128 + ((ch ^ (row & 7)) * 8));
}

// ---------------------------------------------------------------- GEMM 128² (kept for Wo)
// C[M,N] = A[M,K] (bf16 row-major, lda) x B'[N,K] (bf16 row-major, ldb)
// EPI: 0 = f32 store, 1 = bf16 store, 2 = f32 residual add, 3 = bf16 gelu store
template <int EPI>
__launch_bounds__(256)
__global__ void gemm_k(const bf16* __restrict__ A, int lda, long sAb, long sAh,
                       const bf16* __restrict__ Bt, int ldb, long sBb, long sBh,
                       void* __restrict__ Cp, int ldc, long sCb, long sCh,
                       const float* __restrict__ resid, int K, int nH) {
  __shared__ __align__(16) bf16 lsA[2][128 * 32];
  __shared__ __align__(16) bf16 lsB[2][128 * 32];
  const int tid = threadIdx.x;
  const int zb = blockIdx.z / nH, zh = blockIdx.z % nH;
  const int m0 = blockIdx.y * 128, n0 = blockIdx.x * 128;
  const int sr = tid >> 2, sc = (tid & 3) * 8;
  const bf16* Ag = A + zb * sAb + zh * sAh + (long)(m0 + sr) * lda + sc;
  const bf16* Bg = Bt + zb * sBb + zh * sBh + (long)(n0 + sr) * ldb + sc;
  const long a64 = 64L * lda, b64 = 64L * ldb;

  const int lane = tid & 63, wv = tid >> 6;
  const int wm = (wv >> 1) * 64, wn = (wv & 1) * 64;
  const int fl = lane & 15, fg = lane >> 4;

  f32x4 acc[4][4];
#pragma unroll
  for (int i = 0; i < 4; i++)
#pragma unroll
    for (int j = 0; j < 4; j++) acc[i][j] = (f32x4){0.f, 0.f, 0.f, 0.f};

  gll16(Ag, lsA[0] + tid * 8);
  gll16(Ag + a64, lsA[0] + 2048 + tid * 8);
  gll16(Bg, lsB[0] + tid * 8);
  gll16(Bg + b64, lsB[0] + 2048 + tid * 8);
  __syncthreads();

  int it = 0;
  for (int k0 = 0; k0 < K; k0 += 32, it ^= 1) {
    const int nxt = it ^ 1;
    if (k0 + 32 < K) {
      gll16(Ag + k0 + 32, lsA[nxt] + tid * 8);
      gll16(Ag + a64 + k0 + 32, lsA[nxt] + 2048 + tid * 8);
      gll16(Bg + k0 + 32, lsB[nxt] + tid * 8);
      gll16(Bg + b64 + k0 + 32, lsB[nxt] + 2048 + tid * 8);
    }
    s16x8 af[4], bq[4];
#pragma unroll
    for (int i = 0; i < 4; i++) {
      af[i] = *(const s16x8*)(lsA[it] + (wm + i * 16 + fl) * 32 + fg * 8);
      bq[i] = *(const s16x8*)(lsB[it] + (wn + i * 16 + fl) * 32 + fg * 8);
    }
#pragma unroll
    for (int i = 0; i < 4; i++)
#pragma unroll
      for (int j = 0; j < 4; j++)
        acc[i][j] = __builtin_amdgcn_mfma_f32_16x16x32_bf16(af[i], bq[j], acc[i][j], 0, 0, 0);
    __syncthreads();
  }

  const long offC = zb * sCb + zh * sCh;
#pragma unroll
  for (int i = 0; i < 4; i++) {
#pragma unroll
    for (int j = 0; j < 4; j++) {
      const int row = m0 + wm + i * 16 + fg * 4;
      const int col = n0 + wn + j * 16 + fl;
#pragma unroll
      for (int r = 0; r < 4; r++) {
        const long ci = offC + (long)(row + r) * ldc + col;
        float v = acc[i][j][r];
        if (EPI == 0) {
          ((float*)Cp)[ci] = v;
        } else if (EPI == 1) {
          ((bf16*)Cp)[ci] = __float2bfloat16(v);
        } else if (EPI == 2) {
          ((float*)Cp)[ci] = v + resid[ci];
        } else {
          ((bf16*)Cp)[ci] = __float2bfloat16(gelu_tanh(v));
        }
      }
    }
  }
}

// ---------------------------------------------------------------- GEMM 256² 8-phase
// 256x256 tile, BK=64, 512 threads = 8 waves (2M x 4N), wave tile 128x64.
// LDS 128 KiB double-buffered. st-swizzle applied by inverse-swizzling the
// GLOBAL source + swizzled ds_read. Counted vmcnt(6) at phases 4/8 only.
// MM16 orders MFMAs so each accumulator reuse is at distance 8 (not 2).
template <int EPI>
__launch_bounds__(512, 2)
__global__ void gemm256_k(const bf16* __restrict__ A, int lda, long sAb, long sAh,
                          const bf16* __restrict__ Bt, int ldb, long sBb, long sBh,
                          void* __restrict__ Cp, int ldc, long sCb, long sCh,
                          int K, int nH) {
  __shared__ __align__(16) bf16 lsA[2][256 * 64];   // 64 KB
  __shared__ __align__(16) bf16 lsB[2][256 * 64];   // 64 KB
  const int tid = threadIdx.x;
  const int zb = blockIdx.z / nH, zh = blockIdx.z % nH;
  const int m0 = blockIdx.y * 256, n0 = blockIdx.x * 256;

  const int sr = tid >> 3;
  const int sc = (tid & 7) ^ (sr & 7);
  const bf16* Ag = A + zb * sAb + zh * sAh + (long)(m0 + sr) * lda + sc * 8;
  const bf16* Bg = Bt + zb * sBb + zh * sBh +
                   (long)(n0 + (tid >> 8) * 64 + (sr & 31)) * ldb + sc * 8;

  const int lane = tid & 63, wv = tid >> 6;
  const int wm = wv >> 2;          // 0..1
  const int wn = wv & 3;           // 0..3
  const int fl = lane & 15, fg = lane >> 4;

  const int aob = (wm * 64 + fl) * 64;
  const int bob = (wn * 32 + fl) * 64;
  const int s0 = ((fg) ^ (fl & 7)) * 8;
  const int s1 = ((4 + fg) ^ (fl & 7)) * 8;

  s16x8 a[4][2];
  s16x8 bq[2][2][2];
  f32x4 acc[2][4][2][2];
#pragma unroll
  for (int qm = 0; qm < 2; qm++)
#pragma unroll
    for (int mf = 0; mf < 4; mf++)
#pragma unroll
      for (int qn = 0; qn < 2; qn++)
#pragma unroll
        for (int nf = 0; nf < 2; nf++) acc[qm][mf][qn][nf] = (f32x4){0.f, 0.f, 0.f, 0.f};

#define STAGE_A(buf, qm, kt)                                                  \
  do {                                                                        \
    const bf16* _s = Ag + (long)((qm) * 64) * lda + (kt) * 64;                \
    gll16(_s, lsA[buf] + (qm) * 8192 + tid * 8);                              \
    gll16(_s + 128L * lda, lsA[buf] + (qm) * 8192 + 4096 + tid * 8);          \
  } while (0)
#define STAGE_B(buf, qn, kt)                                                  \
  do {                                                                        \
    const bf16* _s = Bg + (long)((qn) * 32) * ldb + (kt) * 64;                \
    gll16(_s, lsB[buf] + (qn) * 8192 + tid * 8);                              \
    gll16(_s + 128L * ldb, lsB[buf] + (qn) * 8192 + 4096 + tid * 8);          \
  } while (0)
#define LDA8(buf, qm)                                                         \
  do {                                                                        \
    const bf16* _p = lsA[buf] + (qm) * 8192 + aob;                            \
    a[0][0] = *(const s16x8*)(_p + s0);        a[0][1] = *(const s16x8*)(_p + s1);        \
    a[1][0] = *(const s16x8*)(_p + 1024 + s0); a[1][1] = *(const s16x8*)(_p + 1024 + s1); \
    a[2][0] = *(const s16x8*)(_p + 2048 + s0); a[2][1] = *(const s16x8*)(_p + 2048 + s1); \
    a[3][0] = *(const s16x8*)(_p + 3072 + s0); a[3][1] = *(const s16x8*)(_p + 3072 + s1); \
  } while (0)
#define LDB4(buf, qn)                                                         \
  do {                                                                        \
    const bf16* _p = lsB[buf] + (qn) * 8192 + bob;                            \
    bq[qn][0][0] = *(const s16x8*)(_p + s0);        bq[qn][0][1] = *(const s16x8*)(_p + s1);        \
    bq[qn][1][0] = *(const s16x8*)(_p + 1024 + s0); bq[qn][1][1] = *(const s16x8*)(_p + 1024 + s1); \
  } while (0)
#define MM16(qm, qn)                                                          \
  do {                                                                        \
    _Pragma("unroll") for (int mf = 0; mf < 4; ++mf)                          \
      acc[qm][mf][qn][0] = __builtin_amdgcn_mfma_f32_16x16x32_bf16(           \
          a[mf][0], bq[qn][0][0], acc[qm][mf][qn][0], 0, 0, 0);               \
    _Pragma("unroll") for (int mf = 0; mf < 4; ++mf)                          \
      acc[qm][mf][qn][1] = __builtin_amdgcn_mfma_f32_16x16x32_bf16(           \
          a[mf][0], bq[qn][1][0], acc[qm][mf][qn][1], 0, 0, 0);               \
    _Pragma("unroll") for (int mf = 0; mf < 4; ++mf)                          \
      acc[qm][mf][qn][0] = __builtin_amdgcn_mfma_f32_16x16x32_bf16(           \
          a[mf][1], bq[qn][0][1], acc[qm][mf][qn][0], 0, 0, 0);               \
    _Pragma("unroll") for (int mf = 0; mf < 4; ++mf)                          \
      acc[qm][mf][qn][1] = __builtin_amdgcn_mfma_f32_16x16x32_bf16(           \
          a[mf][1], bq[qn][1][1], acc[qm][mf][qn][1], 0, 0, 0);               \
  } while (0)
#define PHASE_TAIL(qm, qn)                                                    \
  __builtin_amdgcn_s_barrier();                                               \
  asm volatile("s_waitcnt lgkmcnt(0)" ::: "memory");                          \
  __builtin_amdgcn_sched_barrier(0);                                          \
  __builtin_amdgcn_s_setprio(1);                                              \
  MM16(qm, qn);                                                               \
  __builtin_amdgcn_s_setprio(0);

  const int NT = K >> 6;  // K-tiles of 64; NT even, >= 2

  STAGE_A(0, 0, 0); STAGE_B(0, 0, 0); STAGE_B(0, 1, 0); STAGE_A(0, 1, 0);
  STAGE_A(1, 0, 1); STAGE_B(1, 0, 1); STAGE_B(1, 1, 1);
  asm volatile("s_waitcnt vmcnt(6)" ::: "memory");  // tile0 complete
  __builtin_amdgcn_s_barrier();

  for (int t = 0; t < NT; t += 2) {
    const bool nl = (t + 2 < NT);
    // ---- ph1
    LDA8(0, 0);
    LDB4(0, 0);
    STAGE_A(1, 1, t + 1);
    PHASE_TAIL(0, 0);
    __builtin_amdgcn_s_barrier();
    // ---- ph2
    LDB4(0, 1);
    if (nl) STAGE_A(0, 0, t + 2);
    PHASE_TAIL(0, 1);
    __builtin_amdgcn_s_barrier();
    // ---- ph3
    LDA8(0, 1);
    if (nl) STAGE_B(0, 0, t + 2);
    PHASE_TAIL(1, 0);
    __builtin_amdgcn_s_barrier();
    // ---- ph4
    if (nl) STAGE_B(0, 1, t + 2);
    PHASE_TAIL(1, 1);
    if (nl) asm volatile("s_waitcnt vmcnt(6)" ::: "memory");
    else    asm volatile("s_waitcnt vmcnt(0)" ::: "memory");
    __builtin_amdgcn_s_barrier();
    // ---- ph5
    LDA8(1, 0);
    LDB4(1, 0);
    if (nl) STAGE_A(0, 1, t + 2);
    PHASE_TAIL(0, 0);
    __builtin_amdgcn_s_barrier();
    // ---- ph6
    LDB4(1, 1);
    if (nl) STAGE_A(1, 0, t + 3);
    PHASE_TAIL(0, 1);
    __builtin_amdgcn_s_barrier();
    // ---- ph7
    LDA8(1, 1);
    if (nl) STAGE_B(1, 0, t + 3);
    PHASE_TAIL(1, 0);
    __builtin_amdgcn_s_barrier();
    // ---- ph8
    if (nl) STAGE_B(1, 1, t + 3);
    PHASE_TAIL(1, 1);
    if (nl) asm volatile("s_waitcnt vmcnt(6)" ::: "memory");
    __builtin_amdgcn_s_barrier();
  }

  const long offC = zb * sCb + zh * sCh;
#pragma unroll
  for (int qm = 0; qm < 2; qm++) {
#pragma unroll
    for (int mf = 0; mf < 4; mf++) {
#pragma unroll
      for (int qn = 0; qn < 2; qn++) {
#pragma unroll
        for (int nf = 0; nf < 2; nf++) {
          const int row = m0 + wm * 128 + qm * 64 + mf * 16 + fg * 4;
          const int col = n0 + wn * 64 + qn * 32 + nf * 16 + fl;
#pragma unroll
          for (int r = 0; r < 4; r++) {
            const long ci = offC + (long)(row + r) * ldc + col;
            float v = acc[qm][mf][qn][nf][r];
            if (EPI == 0) {
              ((float*)Cp)[ci] = v;
            } else if (EPI == 1) {
              ((bf16*)Cp)[ci] = __float2bfloat16(v);
            } else {
              ((bf16*)Cp)[ci] = __float2bfloat16(gelu_tanh(v));
            }
          }
        }
      }
    }
  }
#undef STAGE_A
#undef STAGE_B
#undef LDA8
#undef LDB4
#undef MM16
#undef PHASE_TAIL
}

// ---------------------------------------------------------------- fused flash attention
// Per block: one (b,h) and a 128-row q-tile. Loop over kv-tiles of 128:
// S = Q K^T (MFMA), scale+causal/pad mask, online softmax with cross-wave
// row max/sum (16-lane shfl groups + LDS exchange), P through swizzled LDS,
// O += P V (MFMA, fp32 acc). Final O /= l, bf16 store into o_buf layout.
// 4 waves in 2x2 quadrants (same fragment conventions as gemm_k).
__launch_bounds__(256)
__global__ void fa_k(const bf16* __restrict__ qkv, const bf16* __restrict__ Vt,
                     const int* __restrict__ amask, bf16* __restrict__ o_buf,
                     float scale) {
  __shared__ __align__(16) bf16 lsQ[128 * 128];
  __shared__ __align__(16) bf16 lsK[128 * 128];
  __shared__ __align__(16) bf16 lsV[128 * 128];
  __shared__ __align__(16) bf16 lsP[128 * 128];
  __shared__ float smx[2][128];
  __shared__ float sms[2][128];

  const int tid = threadIdx.x;
  const int qi = blockIdx.x, z = blockIdx.y, b = z / H, h = z % H;
  const int q0 = qi * 128;
  const int lane = tid & 63, wv = tid >> 6;
  const int wm = (wv >> 1) * 64, wn = (wv & 1) * 64;
  const int wnb = wn >> 6;  // 0/1
  const int fl = lane & 15, fg = lane >> 4;

  // staging mapping: 16 rows x 16 chunks per gll16 line, 8 lines per tile.
  const int sr = tid >> 4;                 // 0..15
  const int scc = (tid & 15) ^ (sr & 7);   // inverse-swizzled source chunk
  const bf16* Qg = qkv + (long)(b * S + q0 + sr) * D3 + h * DH + scc * 8;
  const bf16* Kg = qkv + (long)(b * S + sr) * D3 + D + h * DH + scc * 8;
  const bf16* Vg = Vt + ((long)z * DH + sr) * S + scc * 8;

#define STAGE_Q()                                                             \
  do { _Pragma("unroll") for (int g = 0; g < 8; g++)                          \
    gll16(Qg + (long)g * 16 * D3, lsQ + g * 2048 + tid * 8); } while (0)
#define STAGE_KT(kv0)                                                         \
  do { _Pragma("unroll") for (int g = 0; g < 8; g++)                          \
    gll16(Kg + (long)((kv0) + g * 16) * D3, lsK + g * 2048 + tid * 8); } while (0)
#define STAGE_VT(kv0)                                                         \
  do { _Pragma("unroll") for (int g = 0; g < 8; g++)                          \
    gll16(Vg + (long)g * 16 * S + (kv0), lsV + g * 2048 + tid * 8); } while (0)

  f32x4 o_acc[4][4];
#pragma unroll
  for (int i = 0; i < 4; i++)
#pragma unroll
    for (int j = 0; j < 4; j++) o_acc[i][j] = (f32x4){0.f, 0.f, 0.f, 0.f};
  float m_st[4][4], l_st[4][4];
#pragma unroll
  for (int i = 0; i < 4; i++)
#pragma unroll
    for (int r = 0; r < 4; r++) { m_st[i][r] = -1e30f; l_st[i][r] = 0.f; }

  STAGE_Q();
  STAGE_KT(0);
  STAGE_VT(0);

  for (int t = 0; t <= qi; ++t) {
    const int kv0 = t * 128;
    asm volatile("s_waitcnt vmcnt(0)" ::: "memory");
    __syncthreads();  // Q (t==0), K(t), V(t) resident

    // ---- S = Q K^T on this tile (wave quadrant 64x64)
    f32x4 s_acc[4][4];
#pragma unroll
    for (int i = 0; i < 4; i++)
#pragma unroll
      for (int j = 0; j < 4; j++) s_acc[i][j] = (f32x4){0.f, 0.f, 0.f, 0.f};
#pragma unroll
    for (int kk = 0; kk < 4; kk++) {
      s16x8 qa[4], kb[4];
#pragma unroll
      for (int i = 0; i < 4; i++) qa[i] = ldfrag(lsQ, wm + i * 16 + fl, kk * 4 + fg);
#pragma unroll
      for (int j = 0; j < 4; j++) kb[j] = ldfrag(lsK, wn + j * 16 + fl, kk * 4 + fg);
#pragma unroll
      for (int i = 0; i < 4; i++)
#pragma unroll
        for (int j = 0; j < 4; j++)
          s_acc[i][j] = __builtin_amdgcn_mfma_f32_16x16x32_bf16(qa[i], kb[j], s_acc[i][j], 0, 0, 0);
    }

    // ---- scale + causal/pad mask
    int am[4];
#pragma unroll
    for (int j = 0; j < 4; j++) am[j] = amask[b * S + kv0 + wn + j * 16 + fl];
#pragma unroll
    for (int i = 0; i < 4; i++)
#pragma unroll
      for (int j = 0; j < 4; j++)
#pragma unroll
        for (int r = 0; r < 4; r++) {
          const int row = q0 + wm + i * 16 + fg * 4 + r;
          const int col = kv0 + wn + j * 16 + fl;
          const bool ok = (col <= row) && (am[j] != 0);
          s_acc[i][j][r] = s_acc[i][j][r] * scale + (ok ? 0.f : -1e9f);
        }

    // ---- row max: own quadrant, then exchange with wn-sibling
    float pm[4][4];
#pragma unroll
    for (int i = 0; i < 4; i++)
#pragma unroll
      for (int r = 0; r < 4; r++) {
        float v = fmaxf(fmaxf(s_acc[i][0][r], s_acc[i][1][r]),
                        fmaxf(s_acc[i][2][r], s_acc[i][3][r]));
        pm[i][r] = grp_max16(v);
      }
    if (fl == 0) {
#pragma unroll
      for (int i = 0; i < 4; i++)
#pragma unroll
        for (int r = 0; r < 4; r++) smx[wnb][wm + i * 16 + fg * 4 + r] = pm[i][r];
    }
    __syncthreads();  // also: all lsK reads of this tile done
    if (t < qi) STAGE_KT(kv0 + 128);  // prefetch next K under softmax+PV

    float al[4][4];
#pragma unroll
    for (int i = 0; i < 4; i++)
#pragma unroll
      for (int r = 0; r < 4; r++) {
        const float other = smx[wnb ^ 1][wm + i * 16 + fg * 4 + r];
        const float tm = fmaxf(pm[i][r], other);
        const float mn = fmaxf(m_st[i][r], tm);
        al[i][r] = __expf(m_st[i][r] - mn);
        m_st[i][r] = mn;
      }

    // ---- p = exp(v - m), row sum (own), exchange
    float ps[4][4];
#pragma unroll
    for (int i = 0; i < 4; i++)
#pragma unroll
      for (int r = 0; r < 4; r++) {
        float sm = 0.f;
#pragma unroll
        for (int j = 0; j < 4; j++) {
          s_acc[i][j][r] = __expf(s_acc[i][j][r] - m_st[i][r]);
          sm += s_acc[i][j][r];
        }
        ps[i][r] = grp_sum16(sm);
      }
    if (fl == 0) {
#pragma unroll
      for (int i = 0; i < 4; i++)
#pragma unroll
        for (int r = 0; r < 4; r++) sms[wnb][wm + i * 16 + fg * 4 + r] = ps[i][r];
    }
    __syncthreads();

    // ---- l update, O rescale, P -> LDS (swizzled)
#pragma unroll
    for (int i = 0; i < 4; i++)
#pragma unroll
      for (int r = 0; r < 4; r++) {
        const float other = sms[wnb ^ 1][wm + i * 16 + fg * 4 + r];
        l_st[i][r] = l_st[i][r] * al[i][r] + ps[i][r] + other;
#pragma unroll
        for (int j = 0; j < 4; j++) o_acc[i][j][r] *= al[i][r];
      }
#pragma unroll
    for (int i = 0; i < 4; i++)
#pragma unroll
      for (int j = 0; j < 4; j++)
#pragma unroll
        for (int r = 0; r < 4; r++) {
          const int prow = wm + i * 16 + fg * 4 + r;
          const int pcol = wn + j * 16 + fl;
          const int ch = pcol >> 3;
          lsP[prow * 128 + ((ch ^ (prow & 7)) * 8) + (pcol & 7)] =
              __float2bfloat16(s_acc[i][j][r]);
        }
    __syncthreads();

    // ---- O += P V (wave quadrant: rows wm half, cols = dh wn half)
#pragma unroll
    for (int kk = 0; kk < 4; kk++) {
      s16x8 pa[4], vb[4];
#pragma unroll
      for (int i = 0; i < 4; i++) pa[i] = ldfrag(lsP, wm + i * 16 + fl, kk * 4 + fg);
#pragma unroll
      for (int j = 0; j < 4; j++) vb[j] = ldfrag(lsV, wn + j * 16 + fl, kk * 4 + fg);
#pragma unroll
      for (int i = 0; i < 4; i++)
#pragma unroll
        for (int j = 0; j < 4; j++)
          o_acc[i][j] = __builtin_amdgcn_mfma_f32_16x16x32_bf16(pa[i], vb[j], o_acc[i][j], 0, 0, 0);
    }
    __syncthreads();  // all lsV reads done
    if (t < qi) STAGE_VT(kv0 + 128);
  }

  // ---- epilogue: O /= l, store bf16 into o_buf [BS][D]
#pragma unroll
  for (int i = 0; i < 4; i++)
#pragma unroll
    for (int r = 0; r < 4; r++) {
      const float inv = 1.f / l_st[i][r];
      const int row = q0 + wm + i * 16 + fg * 4 + r;
#pragma unroll
      for (int j = 0; j < 4; j++) {
        const int col = h * DH + wn + j * 16 + fl;
        o_buf[(long)(b * S + row) * D + col] = __float2bfloat16(o_acc[i][j][r] * inv);
      }
    }
#undef STAGE_Q
#undef STAGE_KT
#undef STAGE_VT
}

// --------------------------------------------- split-K reduce: x += sum(p[0..3])
__launch_bounds__(256)
__global__ void reduce4_k(const float* __restrict__ p, float* __restrict__ x) {
  const long i = (long)blockIdx.x * 256 + threadIdx.x;  // over BS*D/4 float4s
  const long n = (long)BS * D / 4;
  const float4 a = ((const float4*)p)[i];
  const float4 b = ((const float4*)p)[i + n];
  const float4 c = ((const float4*)p)[i + 2 * n];
  const float4 d2 = ((const float4*)p)[i + 3 * n];
  float4 xv = ((float4*)x)[i];
  xv.x += a.x + b.x + c.x + d2.x;
  xv.y += a.y + b.y + c.y + d2.y;
  xv.z += a.z + b.z + c.z + d2.z;
  xv.w += a.w + b.w + c.w + d2.w;
  ((float4*)x)[i] = xv;
}

// ------------------------------------------------- weight transpose + cast
__launch_bounds__(256)
__global__ void transcast_k(const float* __restrict__ in, bf16* __restrict__ out,
                            int R, int C) {
  __shared__ float tile[32][33];
  const int tx = threadIdx.x, ty = threadIdx.y;
  const int c0 = blockIdx.x * 32, r0 = blockIdx.y * 32;
#pragma unroll
  for (int k = 0; k < 4; k++)
    tile[ty + 8 * k][tx] = in[(long)(r0 + ty + 8 * k) * C + c0 + tx];
  __syncthreads();
#pragma unroll
  for (int k = 0; k < 4; k++)
    out[(long)(c0 + ty + 8 * k) * R + r0 + tx] = __float2bfloat16(tile[tx][ty + 8 * k]);
}

// ------------------------------------------------- V transpose per head
__launch_bounds__(256)
__global__ void vtrans_k(const bf16* __restrict__ qkv, bf16* __restrict__ Vt) {
  __shared__ bf16 tile[32][33];
  const int z = blockIdx.z, b = z / H, h = z % H;
  const int d0 = blockIdx.x * 32, s0 = blockIdx.y * 32;
  const int tx = threadIdx.x, ty = threadIdx.y;
#pragma unroll
  for (int k = 0; k < 4; k++)
    tile[ty + 8 * k][tx] =
        qkv[(long)(b * S + s0 + ty + 8 * k) * D3 + 2 * D + h * DH + d0 + tx];
  __syncthreads();
#pragma unroll
  for (int k = 0; k < 4; k++)
    Vt[((long)z * DH + d0 + ty + 8 * k) * S + s0 + tx] = tile[tx][ty + 8 * k];
}

// ---------------------------------------------------------------- LayerNorm
template <typename OutT>
__launch_bounds__(256)
__global__ void ln_k(const float* __restrict__ x, const float* __restrict__ g,
                     const float* __restrict__ bb, OutT* __restrict__ out) {
  __shared__ float sA[4], sB[4];
  const long row = blockIdx.x;
  const int tid = threadIdx.x;
  const float4* xr = (const float4*)(x + row * D);
  float4 v0 = xr[tid], v1 = xr[tid + 256];
  float s = v0.x + v0.y + v0.z + v0.w + v1.x + v1.y + v1.z + v1.w;
  float ss = v0.x * v0.x + v0.y * v0.y + v0.z * v0.z + v0.w * v0.w +
             v1.x * v1.x + v1.y * v1.y + v1.z * v1.z + v1.w * v1.w;
  s = wave_sum(s);
  ss = wave_sum(ss);
  const int lane = tid & 63, wv = tid >> 6;
  if (lane == 0) { sA[wv] = s; sB[wv] = ss; }
  __syncthreads();
  s = sA[0] + sA[1] + sA[2] + sA[3];
  ss = sB[0] + sB[1] + sB[2] + sB[3];
  const float mean = s * (1.f / D);
  const float var = ss * (1.f / D) - mean * mean;
  const float rstd = rsqrtf(var + 1e-5f);
  const float4* gv = (const float4*)g;
  const float4* bv = (const float4*)bb;
  float4 g0 = gv[tid], g1 = gv[tid + 256], c0 = bv[tid], c1 = bv[tid + 256];
  OutT* orow = out + row * D;
  stv(orow, 4 * tid + 0, (v0.x - mean) * rstd * g0.x + c0.x);
  stv(orow, 4 * tid + 1, (v0.y - mean) * rstd * g0.y + c0.y);
  stv(orow, 4 * tid + 2, (v0.z - mean) * rstd * g0.z + c0.z);
  stv(orow, 4 * tid + 3, (v0.w - mean) * rstd * g0.w + c0.w);
  stv(orow, 1024 + 4 * tid + 0, (v1.x - mean) * rstd * g1.x + c1.x);
  stv(orow, 1024 + 4 * tid + 1, (v1.y - mean) * rstd * g1.y + c1.y);
  stv(orow, 1024 + 4 * tid + 2, (v1.z - mean) * rstd * g1.z + c1.z);
  stv(orow, 1024 + 4 * tid + 3, (v1.w - mean) * rstd * g1.w + c1.w);
}

// ---------------------------------------------------------------- embedding
__launch_bounds__(256)
__global__ void embed_k(const int* __restrict__ ids, const float* __restrict__ emb,
                        float* __restrict__ x) {
  const long gid = (long)blockIdx.x * 256 + threadIdx.x;  // over BS * D/4
  const int tok = (int)(gid >> 9);                        // D/4 = 512
  const int c = (int)(gid & 511);
  const int id = ids[tok];
  ((float4*)x)[gid] = ((const float4*)(emb + (long)id * D))[c];
}

// ---------------------------------------------------------------- pooling
__launch_bounds__(256)
__global__ void pool_k(const float* __restrict__ hs, const int* __restrict__ amask,
                       float* __restrict__ pooled) {
  const int d = blockIdx.x * 256 + threadIdx.x;
  const int b = blockIdx.y;
  float s = 0.f, cnt = 0.f;
  for (int i = 0; i < S; i++) {
    const float m = (float)amask[b * S + i];
    s += hs[((long)(b * S + i)) * D + d] * m;
    cnt += m;
  }
  pooled[b * D + d] = s / fmaxf(cnt, 1e-9f);
}

// ---------------------------------------------------------------- head
__launch_bounds__(256)
__global__ void head1_k(const float* __restrict__ pooled, const float* __restrict__ Wc1,
                        const float* __restrict__ bc1, float* __restrict__ t) {
  const int j = blockIdx.x * 256 + threadIdx.x;
  const int b = blockIdx.y;
  float s = bc1[j];
  for (int d = 0; d < D; d++) s += pooled[b * D + d] * Wc1[(long)d * D + j];
  t[b * D + j] = tanhf(s);
}

__launch_bounds__(256)
__global__ void head2_k(const float* __restrict__ t, const float* __restrict__ Wc2,
                        const float* __restrict__ bc2, float* __restrict__ out) {
  __shared__ float red[4][4];
  const int tid = threadIdx.x;
  const int lane = tid & 63, wv = tid >> 6;
  float a[4] = {0.f, 0.f, 0.f, 0.f};  // [b*2+c]
  for (int j = tid; j < D; j += 256) {
    const float w0 = Wc2[j * 2 + 0], w1 = Wc2[j * 2 + 1];
    const float t0 = t[j], t1 = t[D + j];
    a[0] += t0 * w0; a[1] += t0 * w1; a[2] += t1 * w0; a[3] += t1 * w1;
  }
#pragma unroll
  for (int c = 0; c < 4; c++) a[c] = wave_sum(a[c]);
  if (lane == 0) {
#pragma unroll
    for (int c = 0; c < 4; c++) red[wv][c] = a[c];
  }
  __syncthreads();
  if (tid == 0) {
    float tot[4];
#pragma unroll
    for (int c = 0; c < 4; c++) tot[c] = red[0][c] + red[1][c] + red[2][c] + red[3][c];
    const float l00 = tot[0] + bc2[0], l01 = tot[1] + bc2[1];
    const float l10 = tot[2] + bc2[0], l11 = tot[3] + bc2[1];
    out[0] = 1.f / (1.f + __expf(l00 - l01));
    out[1] = 1.f / (1.f + __expf(l10 - l11));
  }
}

// ---------------------------------------------------------------- launcher
extern "C" void kernel_launch(void* const* d_in, const int* in_sizes, int n_in,
                              void* d_out, int out_size, void* d_ws, size_t ws_size,
                              hipStream_t stream) {
  (void)in_sizes; (void)n_in; (void)out_size; (void)ws_size;
  const int*   ids   = (const int*)d_in[0];
  const int*   amask = (const int*)d_in[1];
  const float* emb   = (const float*)d_in[2];
  const float* ln1g  = (const float*)d_in[3];
  const float* ln1b  = (const float*)d_in[4];
  const float* Wqkv  = (const float*)d_in[5];
  const float* Wo    = (const float*)d_in[6];
  const float* ln2g  = (const float*)d_in[7];
  const float* ln2b  = (const float*)d_in[8];
  const float* W1    = (const float*)d_in[9];
  const float* W2    = (const float*)d_in[10];
  const float* lnfg  = (const float*)d_in[11];
  const float* lnfb  = (const float*)d_in[12];
  const float* Wc1   = (const float*)d_in[13];
  const float* bc1   = (const float*)d_in[14];
  const float* Wc2   = (const float*)d_in[15];
  const float* bc2   = (const float*)d_in[16];
  float* out = (float*)d_out;

  char* ws = (char*)d_ws;
  size_t off = 0;
  auto alloc = [&](size_t bytes) {
    size_t r = off;
    off += (bytes + 255) & ~(size_t)255;
    return r;
  };
  bf16* Wqkv_t = (bf16*)(ws + alloc((size_t)D3 * D * 2));
  bf16* Wo_t   = (bf16*)(ws + alloc((size_t)D * D * 2));
  bf16* W1_t   = (bf16*)(ws + alloc((size_t)FF * D * 2));
  bf16* W2_t   = (bf16*)(ws + alloc((size_t)D * FF * 2));
  float* x     = (float*)(ws + alloc((size_t)BS * D * 4));
  bf16* h      = (bf16*)(ws + alloc((size_t)BS * D * 2));
  bf16* qkv    = (bf16*)(ws + alloc((size_t)BS * D3 * 2));
  bf16* Vt     = (bf16*)(ws + alloc((size_t)BH * DH * S * 2));
  bf16* o_buf  = (bf16*)(ws + alloc((size_t)BS * D * 2));
  float* pooled= (float*)(ws + alloc((size_t)NB * D * 4));
  float* tb    = (float*)(ws + alloc((size_t)NB * D * 4));
  char* big    = ws + alloc((size_t)BH * S * S * 4);  // ff+partials / hs union
  bf16*  ffb    = (bf16*)big;                          // [BS][FF] bf16
  float* hs     = (float*)big;
  float* parts  = (float*)(big + ((size_t)BS * FF * 2 + 255 & ~(size_t)255));

  const float scale = 0.088388347648318447f;  // 1/sqrt(128)
  dim3 blk(256);
  dim3 blk5(512);
  dim3 tblk(32, 8);

  embed_k<<<4096, blk, 0, stream>>>(ids, emb, x);

  for (int l = 0; l < L; l++) {
    transcast_k<<<dim3(D3 / 32, D / 32), tblk, 0, stream>>>(Wqkv + (size_t)l * D * D3, Wqkv_t, D, D3);
    transcast_k<<<dim3(D / 32, D / 32), tblk, 0, stream>>>(Wo + (size_t)l * D * D, Wo_t, D, D);
    transcast_k<<<dim3(FF / 32, D / 32), tblk, 0, stream>>>(W1 + (size_t)l * D * FF, W1_t, D, FF);
    transcast_k<<<dim3(D / 32, FF / 32), tblk, 0, stream>>>(W2 + (size_t)l * FF * D, W2_t, FF, D);

    // h = LN1(x)
    ln_k<bf16><<<BS, blk, 0, stream>>>(x, ln1g + (size_t)l * D, ln1b + (size_t)l * D, h);
    // qkv = h @ Wqkv  (256² 8-phase)
    gemm256_k<1><<<dim3(D3 / 256, BS / 256, 1), blk5, 0, stream>>>(
        h, D, 0, 0, Wqkv_t, D, 0, 0, qkv, D3, 0, 0, D, 1);
    // Vt
    vtrans_k<<<dim3(DH / 32, S / 32, BH), tblk, 0, stream>>>(qkv, Vt);
    // fused flash attention: QK^T -> softmax -> PV, causal + pad mask
    fa_k<<<dim3(S / 128, BH), blk, 0, stream>>>(qkv, Vt, amask, o_buf, scale);
    // x = x + o @ Wo
    gemm_k<2><<<dim3(D / 128, BS / 128, 1), blk, 0, stream>>>(
        o_buf, D, 0, 0, Wo_t, D, 0, 0, x, D, 0, 0, x, D, 1);
    // h = LN2(x)
    ln_k<bf16><<<BS, blk, 0, stream>>>(x, ln2g + (size_t)l * D, ln2b + (size_t)l * D, h);
    // ff = gelu(h @ W1)  (256² 8-phase)
    gemm256_k<3><<<dim3(FF / 256, BS / 256, 1), blk5, 0, stream>>>(
        h, D, 0, 0, W1_t, D, 0, 0, ffb, FF, 0, 0, D, 1);
    // x = x + ff @ W2 — split-K=4 (256² 8-phase)
    gemm256_k<0><<<dim3(D / 256, BS / 256, 4), blk5, 0, stream>>>(
        ffb, FF, 0, 2048, W2_t, FF, 0, 2048,
        parts, D, 0, (long)BS * D, 2048, 4);
    reduce4_k<<<dim3(BS * D / 4 / 256), blk, 0, stream>>>(parts, x);
  }

  ln_k<float><<<BS, blk, 0, stream>>>(x, lnfg, lnfb, hs);
  pool_k<<<dim3(D / 256, NB), blk, 0, stream>>>(hs, amask, pooled);
  head1_k<<<dim3(D / 256, NB), blk, 0, stream>>>(pooled, Wc1, bc1, tb);
  head2_k<<<1, blk, 0, stream>>>(tb, Wc2, bc2, out);
}